// Round 4
// baseline (27811.063 us; speedup 1.0000x reference)
//
#include <hip/hip_runtime.h>
#include <hip/hip_bf16.h>

typedef __hip_bfloat16 bf16;

__device__ __forceinline__ float b2f(bf16 v){ return __bfloat162float(v); }
__device__ __forceinline__ bf16 f2b(float v){ return __float2bfloat16(v); }
__device__ __forceinline__ float ldf(const bf16* p){ return __bfloat162float(*p); }
__device__ __forceinline__ float ldf(const float* p){ return *p; }

__device__ __forceinline__ void store_bf16x2(bf16* p, float a, float b){
  union { bf16 h[2]; unsigned u; } t;
  t.h[0] = f2b(a); t.h[1] = f2b(b);
  *reinterpret_cast<unsigned*>(p) = t.u;
}

// ---------------- weight repacks (f32 inputs) ----------------
// w[Cout][Cin][KK] -> o[KK][Cin][Cout]  (encoder / proj / out conv)
__global__ void repack_tco(const float* __restrict__ w, float* __restrict__ o,
                           int Cout, int Cin, int KK){
  int i = blockIdx.x*256 + threadIdx.x;
  int total = Cout*Cin*KK;
  if (i >= total) return;
  int co = i / (Cin*KK);
  int r  = i - co*(Cin*KK);
  int ci = r / KK;
  int t  = r - ci*KK;
  o[((size_t)t*Cin + ci)*Cout + co] = w[i];
}

// w[Cout][Cin][16] -> o[Cin][Cout][16] (decoder: 16 contiguous taps per co)
__global__ void repack_cot(const float* __restrict__ w, float* __restrict__ o,
                           int Cout, int Cin){
  int i = blockIdx.x*256 + threadIdx.x;
  int total = Cout*Cin*16;
  if (i >= total) return;
  int co = i / (Cin*16);
  int r  = i - co*(Cin*16);
  int ci = r >> 4;
  int t  = r & 15;
  o[((size_t)ci*Cout + co)*16 + t] = w[i];
}

// ---------------- encoder: conv k=4 s=2 p=1, f32 accumulate ----------------
template<int CO_BLK>
__global__ void conv4x4s2(const float* __restrict__ x, const float* __restrict__ wp,
                          const float* __restrict__ bias, float* __restrict__ y,
                          int Cin, int Hin, int Win, int Cout, int Hout, int Wout,
                          int relu)
{
  int sp = blockIdx.x*256 + threadIdx.x;
  if (sp >= Hout*Wout) return;
  int oh = sp / Wout, ow = sp - oh*Wout;
  int n = blockIdx.z, co0 = blockIdx.y*CO_BLK;
  float acc[CO_BLK];
  #pragma unroll
  for (int j=0;j<CO_BLK;j++) acc[j] = bias[co0+j];
  const float* xn = x + (size_t)n*Cin*Hin*Win;
  size_t HWi = (size_t)Hin*Win;
  for (int kh=0; kh<4; kh++){
    int ih = 2*oh - 1 + kh;
    bool vh = ((unsigned)ih < (unsigned)Hin);
    for (int kw=0; kw<4; kw++){
      int iw = 2*ow - 1 + kw;
      bool v = vh && ((unsigned)iw < (unsigned)Win);
      const float* wr = wp + ((size_t)(kh*4+kw)*Cin)*Cout + co0;
      const float* xp = xn + (size_t)ih*Win + iw;
      for (int ci=0; ci<Cin; ci++){
        float xv = v ? xp[(size_t)ci*HWi] : 0.f;
        #pragma unroll
        for (int j=0;j<CO_BLK;j++)
          acc[j] = fmaf(xv, wr[(size_t)ci*Cout + j], acc[j]);
      }
    }
  }
  size_t HWo = (size_t)Hout*Wout;
  float* yp = y + ((size_t)n*Cout + co0)*HWo + sp;
  #pragma unroll
  for (int j=0;j<CO_BLK;j++){
    float r = acc[j];
    if (relu) r = fmaxf(r, 0.f);
    yp[(size_t)j*HWo] = r;
  }
}

// ---------------- proj: 1x1 conv; writes z (f32) straight to d_out region ----------------
template<int CO_BLK>
__global__ void conv1x1(const float* __restrict__ x, const float* __restrict__ wp,
                        const float* __restrict__ bias, float* __restrict__ z,
                        int Cin, int HW, int Cout)
{
  int sp = blockIdx.x*256 + threadIdx.x;
  if (sp >= HW) return;
  int n = blockIdx.z, co0 = blockIdx.y*CO_BLK;
  float acc[CO_BLK];
  #pragma unroll
  for (int j=0;j<CO_BLK;j++) acc[j] = bias[co0+j];
  const float* xp = x + (size_t)n*Cin*HW + sp;
  for (int ci=0; ci<Cin; ci++){
    float xv = xp[(size_t)ci*HW];
    #pragma unroll
    for (int j=0;j<CO_BLK;j++)
      acc[j] = fmaf(xv, wp[(size_t)ci*Cout + co0 + j], acc[j]);
  }
  size_t base = ((size_t)n*Cout + co0)*HW + sp;
  #pragma unroll
  for (int j=0;j<CO_BLK;j++)
    z[base + (size_t)j*HW] = acc[j];
}

// ---------------- VQ: per-wave argmin over 1024 codes (f32 codebook) ----------------
// block = 256 = 4 waves, each wave one spatial position
__global__ void vq_argmin(const float* __restrict__ z, const float* __restrict__ cbf,
                          float* __restrict__ zq, float* __restrict__ zqst)
{
  __shared__ float lz[4][64];
  int t = threadIdx.x;
  int q = t >> 6, l = t & 63;
  int p = blockIdx.x*4 + q;
  int n = p >> 10, hw = p & 1023;
  size_t zbase = ((size_t)n*64)*1024 + hw;
  float zl = z[zbase + (size_t)l*1024];
  lz[q][l] = zl;
  __syncthreads();
  float best = 3.0e38f; int bi = 0;
  const float* zv = &lz[q][0];
  for (int c = l; c < 1024; c += 64){
    const float4* row = reinterpret_cast<const float4*>(cbf + (size_t)c*64);
    float d = 0.f;
    #pragma unroll
    for (int v4 = 0; v4 < 16; v4++){
      float4 cv = row[v4];
      int j0 = v4*4;
      float d0 = zv[j0+0]-cv.x; d = fmaf(d0,d0,d);
      float d1 = zv[j0+1]-cv.y; d = fmaf(d1,d1,d);
      float d2 = zv[j0+2]-cv.z; d = fmaf(d2,d2,d);
      float d3 = zv[j0+3]-cv.w; d = fmaf(d3,d3,d);
    }
    if (d < best){ best = d; bi = c; }   // candidates ascend within lane -> strict <
  }
  #pragma unroll
  for (int off = 32; off > 0; off >>= 1){
    float od = __shfl_down(best, off, 64);
    int   oi = __shfl_down(bi,  off, 64);
    if (od < best || (od == best && oi < bi)){ best = od; bi = oi; }
  }
  bi = __shfl(bi, 0, 64);
  float qv = cbf[(size_t)bi*64 + l];
  size_t oidx = zbase + (size_t)l*1024;
  zq[oidx]   = qv;
  zqst[oidx] = zl + (qv - zl);
}

// ---------------- decoder: convT k=4 s=2 (JAX SAME, transpose_kernel=False) ----------------
// out[2i  ,2j  ] = w[0][0]x[i-1][j-1] + w[0][2]x[i-1][j  ] + w[2][0]x[i  ][j-1] + w[2][2]x[i  ][j  ]
// out[2i  ,2j+1] = w[0][1]x[i-1][j  ] + w[0][3]x[i-1][j+1] + w[2][1]x[i  ][j  ] + w[2][3]x[i  ][j+1]
// out[2i+1,2j  ] = w[1][0]x[i  ][j-1] + w[1][2]x[i  ][j  ] + w[3][0]x[i+1][j-1] + w[3][2]x[i+1][j  ]
// out[2i+1,2j+1] = w[1][1]x[i  ][j  ] + w[1][3]x[i  ][j+1] + w[3][1]x[i+1][j  ] + w[3][3]x[i+1][j+1]
template<typename InT, int CO_BLK>
__global__ void convT4x4s2(const InT* __restrict__ x, const float* __restrict__ wq,
                           const float* __restrict__ bias, bf16* __restrict__ y,
                           int Cin, int Hin, int Win, int Cout, int relu)
{
  int sp = blockIdx.x*256 + threadIdx.x;
  int HWin = Hin*Win;
  if (sp >= HWin) return;
  int qi = sp / Win, qj = sp - qi*Win;
  int n = blockIdx.z, co0 = blockIdx.y*CO_BLK;
  float a00[CO_BLK], a01[CO_BLK], a10[CO_BLK], a11[CO_BLK];
  #pragma unroll
  for (int j=0;j<CO_BLK;j++){
    float bv = bias[co0+j];
    a00[j]=bv; a01[j]=bv; a10[j]=bv; a11[j]=bv;
  }
  bool vmh = qi > 0, vph = qi+1 < Hin, vmw = qj > 0, vpw = qj+1 < Win;
  const InT* xn = x + (size_t)n*Cin*HWin + (size_t)qi*Win + qj;
  for (int ci=0; ci<Cin; ci++){
    const InT* xc = xn + (size_t)ci*HWin;
    float xmm = (vmh && vmw) ? ldf(xc - Win - 1) : 0.f;
    float xm0 =  vmh         ? ldf(xc - Win    ) : 0.f;
    float xm1 = (vmh && vpw) ? ldf(xc - Win + 1) : 0.f;
    float x0m =  vmw         ? ldf(xc - 1      ) : 0.f;
    float x00 =                ldf(xc          );
    float x01 =  vpw         ? ldf(xc + 1      ) : 0.f;
    float x1m = (vph && vmw) ? ldf(xc + Win - 1) : 0.f;
    float x10 =  vph         ? ldf(xc + Win    ) : 0.f;
    float x11 = (vph && vpw) ? ldf(xc + Win + 1) : 0.f;
    const float* w = wq + ((size_t)ci*Cout + co0)*16;
    #pragma unroll
    for (int j=0;j<CO_BLK;j++){
      const float* wj = w + j*16;
      a00[j] += wj[0]*xmm + wj[2]*xm0 + wj[8]*x0m  + wj[10]*x00;
      a01[j] += wj[1]*xm0 + wj[3]*xm1 + wj[9]*x00  + wj[11]*x01;
      a10[j] += wj[4]*x0m + wj[6]*x00 + wj[12]*x1m + wj[14]*x10;
      a11[j] += wj[5]*x00 + wj[7]*x01 + wj[13]*x10 + wj[15]*x11;
    }
  }
  int Wout = Win*2;
  size_t HWout = (size_t)HWin*4;
  size_t obase = ((size_t)n*Cout + co0)*HWout + (size_t)(2*qi)*Wout + 2*qj;
  #pragma unroll
  for (int j=0;j<CO_BLK;j++){
    float r00=a00[j], r01=a01[j], r10=a10[j], r11=a11[j];
    if (relu){ r00=fmaxf(r00,0.f); r01=fmaxf(r01,0.f); r10=fmaxf(r10,0.f); r11=fmaxf(r11,0.f); }
    bf16* yp = y + obase + (size_t)j*HWout;
    store_bf16x2(yp,        r00, r01);
    store_bf16x2(yp + Wout, r10, r11);
  }
}

// ---------------- out conv: 3x3 p=1 s=1, Cout=3, f32 out ----------------
__global__ void conv3x3_out(const bf16* __restrict__ x, const float* __restrict__ wp,
                            const float* __restrict__ bias, float* __restrict__ y,
                            int Cin, int H, int W)
{
  int sp = blockIdx.x*256 + threadIdx.x;
  if (sp >= H*W) return;
  int oh = sp / W, ow = sp - oh*W;
  int n = blockIdx.z;
  float a0 = bias[0], a1 = bias[1], a2 = bias[2];
  const bf16* xn = x + (size_t)n*Cin*H*W;
  size_t HW = (size_t)H*W;
  for (int kh=0; kh<3; kh++){
    int ih = oh - 1 + kh;
    bool vh = ((unsigned)ih < (unsigned)H);
    for (int kw=0; kw<3; kw++){
      int iw = ow - 1 + kw;
      bool v = vh && ((unsigned)iw < (unsigned)W);
      const float* wr = wp + (size_t)(kh*3+kw)*Cin*3;
      const bf16* xp = xn + (size_t)ih*W + iw;
      for (int ci=0; ci<Cin; ci++){
        float xv = v ? ldf(xp + (size_t)ci*HW) : 0.f;
        a0 = fmaf(xv, wr[ci*3+0], a0);
        a1 = fmaf(xv, wr[ci*3+1], a1);
        a2 = fmaf(xv, wr[ci*3+2], a2);
      }
    }
  }
  float* yp = y + (size_t)n*3*HW + sp;
  yp[0]    = a0;
  yp[HW]   = a1;
  yp[2*HW] = a2;
}

// ---------------- workspace layout (bytes) ----------------
static const size_t W_WENC0 = 0;           //  24,576
static const size_t W_WENC1 = 24576;       //  2,097,152
static const size_t W_WENC2 = 2121728;     //  8,388,608
static const size_t W_WPROJ = 10510336;    //  131,072
static const size_t W_WDEC0 = 10641408;    //  2,097,152
static const size_t W_WDEC1 = 12738560;    //  8,388,608
static const size_t W_WDEC2 = 21127168;    //  2,097,152
static const size_t W_WOUT  = 23224320;    //  13,824
static const size_t W_BYTES = 23238144;
// per-image activations:
//   A (16 MiB): h0 f32 (8 MiB) then d2 bf16 (16 MiB)
//   Bg (8 MiB): h1 f32 (4 MiB) then d1 bf16 (8 MiB)
//   C  (4 MiB): h2 f32 (2 MiB) then d0 bf16 (4 MiB)
//   zqs f32 (256 KiB)
static const size_t PER_IMG = 29622272;    // 28.25 MiB

extern "C" void kernel_launch(void* const* d_in, const int* in_sizes, int n_in,
                              void* d_out, int out_size, void* d_ws, size_t ws_size,
                              hipStream_t stream)
{
  const float* x      = (const float*)d_in[0];
  const float* enc_w0 = (const float*)d_in[1];
  const float* enc_b0 = (const float*)d_in[2];
  const float* enc_w1 = (const float*)d_in[3];
  const float* enc_b1 = (const float*)d_in[4];
  const float* enc_w2 = (const float*)d_in[5];
  const float* enc_b2 = (const float*)d_in[6];
  const float* proj_w = (const float*)d_in[7];
  const float* proj_b = (const float*)d_in[8];
  const float* dec_w0 = (const float*)d_in[9];
  const float* dec_b0 = (const float*)d_in[10];
  const float* dec_w1 = (const float*)d_in[11];
  const float* dec_b1 = (const float*)d_in[12];
  const float* dec_w2 = (const float*)d_in[13];
  const float* dec_b2 = (const float*)d_in[14];
  const float* out_w  = (const float*)d_in[15];
  const float* out_b  = (const float*)d_in[16];
  const float* cb     = (const float*)d_in[17];

  float* out    = (float*)d_out;
  float* recon  = out;             // 16*3*256*256 = 3,145,728 f32
  float* z_out  = out + 3145728;   // 16*64*32*32  = 1,048,576 f32
  float* zq_out = out + 4194304;   // 16*64*32*32  = 1,048,576 f32

  char* ws = (char*)d_ws;
  float* wenc0 = (float*)(ws + W_WENC0);
  float* wenc1 = (float*)(ws + W_WENC1);
  float* wenc2 = (float*)(ws + W_WENC2);
  float* wproj = (float*)(ws + W_WPROJ);
  float* wdec0 = (float*)(ws + W_WDEC0);
  float* wdec1 = (float*)(ws + W_WDEC1);
  float* wdec2 = (float*)(ws + W_WDEC2);
  float* wout  = (float*)(ws + W_WOUT);

  // pick the largest chunk size that fits ws_size
  int B = 16;
  while (B > 1 && W_BYTES + (size_t)B*PER_IMG > ws_size) B >>= 1;

  char* act = ws + W_BYTES;
  size_t szA  = (size_t)B*16777216;
  size_t szBg = (size_t)B*8388608;
  size_t szC  = (size_t)B*4194304;
  float* h0  = (float*)(act);
  bf16*  d2  = (bf16*) (act);
  float* h1  = (float*)(act + szA);
  bf16*  d1  = (bf16*) (act + szA);
  float* h2  = (float*)(act + szA + szBg);
  bf16*  d0  = (bf16*) (act + szA + szBg);
  float* zqs = (float*)(act + szA + szBg + szC);

  auto nb = [](int total){ return dim3((unsigned)((total + 255) / 256)); };

  // repack weights (once per call)
  repack_tco<<<nb(128*3*16),  256, 0, stream>>>(enc_w0, wenc0, 128, 3, 16);
  repack_tco<<<nb(256*128*16),256, 0, stream>>>(enc_w1, wenc1, 256, 128, 16);
  repack_tco<<<nb(512*256*16),256, 0, stream>>>(enc_w2, wenc2, 512, 256, 16);
  repack_tco<<<nb(64*512*1),  256, 0, stream>>>(proj_w, wproj, 64, 512, 1);
  repack_cot<<<nb(512*64*16), 256, 0, stream>>>(dec_w0, wdec0, 512, 64);
  repack_cot<<<nb(256*512*16),256, 0, stream>>>(dec_w1, wdec1, 256, 512);
  repack_cot<<<nb(128*256*16),256, 0, stream>>>(dec_w2, wdec2, 128, 256);
  repack_tco<<<nb(3*128*9),   256, 0, stream>>>(out_w, wout, 3, 128, 9);

  for (int n0 = 0; n0 < 16; n0 += B){
    const float* xc  = x      + (size_t)n0*3*65536;
    float* reconc    = recon  + (size_t)n0*3*65536;
    float* z_outc    = z_out  + (size_t)n0*65536;
    float* zq_outc   = zq_out + (size_t)n0*65536;

    conv4x4s2<8><<<dim3(64,16,B), 256, 0, stream>>>(xc, wenc0, enc_b0, h0, 3,   256,256, 128, 128,128, 1);
    conv4x4s2<8><<<dim3(16,32,B), 256, 0, stream>>>(h0, wenc1, enc_b1, h1, 128, 128,128, 256, 64,64,   1);
    conv4x4s2<8><<<dim3(4, 64,B), 256, 0, stream>>>(h1, wenc2, enc_b2, h2, 256, 64,64,   512, 32,32,   1);
    conv1x1<8><<<dim3(4, 8, B), 256, 0, stream>>>(h2, wproj, proj_b, z_outc, 512, 1024, 64);

    vq_argmin<<<dim3(256*B), 256, 0, stream>>>(z_outc, cb, zq_outc, zqs);

    convT4x4s2<float,8><<<dim3(4, 64,B), 256, 0, stream>>>(zqs, wdec0, dec_b0, d0, 64,  32,32,   512, 1);
    convT4x4s2<bf16, 8><<<dim3(16,32,B), 256, 0, stream>>>(d0,  wdec1, dec_b1, d1, 512, 64,64,   256, 1);
    convT4x4s2<bf16, 8><<<dim3(64,16,B), 256, 0, stream>>>(d1,  wdec2, dec_b2, d2, 256, 128,128, 128, 1);

    conv3x3_out<<<dim3(256,1,B), 256, 0, stream>>>(d2, wout, out_b, reconc, 128, 256, 256);
  }
}

// Round 5
// 10391.968 us; speedup vs baseline: 2.6762x; 2.6762x over previous
//
#include <hip/hip_runtime.h>
#include <hip/hip_bf16.h>

typedef __hip_bfloat16 bf16;
typedef __attribute__((ext_vector_type(8))) short short8;
typedef __attribute__((ext_vector_type(4))) float f32x4;

__device__ __forceinline__ float b2f(bf16 v){ return __bfloat162float(v); }
__device__ __forceinline__ bf16 f2b(float v){ return __float2bfloat16(v); }
__device__ __forceinline__ float ldf(const bf16* p){ return __bfloat162float(*p); }
__device__ __forceinline__ float ldf(const float* p){ return *p; }

__device__ __forceinline__ unsigned short bfbits(float v){
  union{ bf16 h; unsigned short u; } t; t.h = f2b(v); return t.u;
}

// ---------------- weight repacks ----------------
// w[Cout][Cin][KK] f32 -> o[KK][Cin][Cout] f32  (encoder / proj / out conv)
__global__ void repack_tco(const float* __restrict__ w, float* __restrict__ o,
                           int Cout, int Cin, int KK){
  int i = blockIdx.x*256 + threadIdx.x;
  int total = Cout*Cin*KK;
  if (i >= total) return;
  int co = i / (Cin*KK);
  int r  = i - co*(Cin*KK);
  int ci = r / KK;
  int t  = r - ci*KK;
  o[((size_t)t*Cin + ci)*Cout + co] = w[i];
}

// w[Cout][Cin][16] f32 -> o[tap][Cout][Cin] bf16  (decoder MFMA A-operand)
__global__ void repack_tcc_bf16(const float* __restrict__ w, short* __restrict__ o,
                                int Cout, int Cin){
  int i = blockIdx.x*256 + threadIdx.x;
  int total = Cout*Cin*16;
  if (i >= total) return;
  int co = i / (Cin*16);
  int r  = i - co*(Cin*16);
  int ci = r >> 4;
  int t  = r & 15;
  o[((size_t)t*Cout + co)*Cin + ci] = (short)bfbits(w[i]);
}

// ---------------- encoder: conv k=4 s=2 p=1, f32 accumulate ----------------
template<int CO_BLK>
__global__ void conv4x4s2(const float* __restrict__ x, const float* __restrict__ wp,
                          const float* __restrict__ bias, float* __restrict__ y,
                          int Cin, int Hin, int Win, int Cout, int Hout, int Wout,
                          int relu)
{
  int sp = blockIdx.x*256 + threadIdx.x;
  if (sp >= Hout*Wout) return;
  int oh = sp / Wout, ow = sp - oh*Wout;
  int n = blockIdx.z, co0 = blockIdx.y*CO_BLK;
  float acc[CO_BLK];
  #pragma unroll
  for (int j=0;j<CO_BLK;j++) acc[j] = bias[co0+j];
  const float* xn = x + (size_t)n*Cin*Hin*Win;
  size_t HWi = (size_t)Hin*Win;
  for (int kh=0; kh<4; kh++){
    int ih = 2*oh - 1 + kh;
    bool vh = ((unsigned)ih < (unsigned)Hin);
    for (int kw=0; kw<4; kw++){
      int iw = 2*ow - 1 + kw;
      bool v = vh && ((unsigned)iw < (unsigned)Win);
      const float* wr = wp + ((size_t)(kh*4+kw)*Cin)*Cout + co0;
      const float* xp = xn + (size_t)ih*Win + iw;
      for (int ci=0; ci<Cin; ci++){
        float xv = v ? xp[(size_t)ci*HWi] : 0.f;
        #pragma unroll
        for (int j=0;j<CO_BLK;j++)
          acc[j] = fmaf(xv, wr[(size_t)ci*Cout + j], acc[j]);
      }
    }
  }
  size_t HWo = (size_t)Hout*Wout;
  float* yp = y + ((size_t)n*Cout + co0)*HWo + sp;
  #pragma unroll
  for (int j=0;j<CO_BLK;j++){
    float r = acc[j];
    if (relu) r = fmaxf(r, 0.f);
    yp[(size_t)j*HWo] = r;
  }
}

// ---------------- proj: 1x1 conv; writes z (f32) straight to d_out region ----------------
template<int CO_BLK>
__global__ void conv1x1(const float* __restrict__ x, const float* __restrict__ wp,
                        const float* __restrict__ bias, float* __restrict__ z,
                        int Cin, int HW, int Cout)
{
  int sp = blockIdx.x*256 + threadIdx.x;
  if (sp >= HW) return;
  int n = blockIdx.z, co0 = blockIdx.y*CO_BLK;
  float acc[CO_BLK];
  #pragma unroll
  for (int j=0;j<CO_BLK;j++) acc[j] = bias[co0+j];
  const float* xp = x + (size_t)n*Cin*HW + sp;
  for (int ci=0; ci<Cin; ci++){
    float xv = xp[(size_t)ci*HW];
    #pragma unroll
    for (int j=0;j<CO_BLK;j++)
      acc[j] = fmaf(xv, wp[(size_t)ci*Cout + co0 + j], acc[j]);
  }
  size_t base = ((size_t)n*Cout + co0)*HW + sp;
  #pragma unroll
  for (int j=0;j<CO_BLK;j++)
    z[base + (size_t)j*HW] = acc[j];
}

// ---------------- VQ: per-wave argmin over 1024 codes ----------------
// block = 256 = 4 waves, each wave one spatial position.
// z_q written f32 to d_out; straight-through z_q_st written bf16 for MFMA decoder.
__global__ void vq_argmin(const float* __restrict__ z, const float* __restrict__ cbf,
                          float* __restrict__ zq, bf16* __restrict__ zqst)
{
  __shared__ float lz[4][64];
  int t = threadIdx.x;
  int q = t >> 6, l = t & 63;
  int p = blockIdx.x*4 + q;
  int n = p >> 10, hw = p & 1023;
  size_t zbase = ((size_t)n*64)*1024 + hw;
  float zl = z[zbase + (size_t)l*1024];
  lz[q][l] = zl;
  __syncthreads();
  float best = 3.0e38f; int bi = 0;
  const float* zv = &lz[q][0];
  for (int c = l; c < 1024; c += 64){
    const float4* row = reinterpret_cast<const float4*>(cbf + (size_t)c*64);
    float d = 0.f;
    #pragma unroll
    for (int v4 = 0; v4 < 16; v4++){
      float4 cv = row[v4];
      int j0 = v4*4;
      float d0 = zv[j0+0]-cv.x; d = fmaf(d0,d0,d);
      float d1 = zv[j0+1]-cv.y; d = fmaf(d1,d1,d);
      float d2 = zv[j0+2]-cv.z; d = fmaf(d2,d2,d);
      float d3 = zv[j0+3]-cv.w; d = fmaf(d3,d3,d);
    }
    if (d < best){ best = d; bi = c; }   // candidates ascend within lane -> strict <
  }
  #pragma unroll
  for (int off = 32; off > 0; off >>= 1){
    float od = __shfl_down(best, off, 64);
    int   oi = __shfl_down(bi,  off, 64);
    if (od < best || (od == best && oi < bi)){ best = od; bi = oi; }
  }
  bi = __shfl(bi, 0, 64);
  float qv = cbf[(size_t)bi*64 + l];
  size_t oidx = zbase + (size_t)l*1024;
  zq[oidx]   = qv;
  zqst[oidx] = f2b(zl + (qv - zl));
}

// ---------------- decoder: convT k=4 s=2 via MFMA 16x16x32 bf16 ----------------
// Per parity (ph,pw), out[2i+ph][2j+pw] = bias + sum_u,v W[ph+2u][pw+2v] . x[i+u-1+ph][j+v-1+pw]
// MFMA roles: A = weights [tap][co][ci] (m=co, k=ci), B = x tile in LDS (k=ci, n=spatial).
// Block: 4 waves; TS=64 -> waves = 2 spatial-halves x 2 co-halves (block 64sp x 64co);
//        TS=32 -> waves = 4 co-quarters (block 32sp x 128co).
template<int TS>
__global__ __launch_bounds__(256) void convT_mfma(
    const short* __restrict__ x, const short* __restrict__ wb,
    const float* __restrict__ bias, short* __restrict__ y,
    int Cin, int Hin, int Win, int Cout, int relu)
{
  constexpr int SHW  = TS/32;          // spatial wave-halves
  constexpr int COB  = (4/SHW)*32;     // co covered per block
  constexpr int COLS = TS + 2;         // staged cols (halo 1 each side)
  constexpr int CIP  = 40;             // ci pitch (16B-aligned rows)
  __shared__ __align__(16) short lds[3*COLS*CIP];

  int tid  = threadIdx.x;
  int w    = tid >> 6, lane = tid & 63;
  int sh   = w % SHW, ch = w / SHW;
  int n15  = lane & 15, quad = lane >> 4;
  int i0   = blockIdx.y;
  int j0   = blockIdx.x * TS;
  int nct  = Cout / COB;
  int ct   = blockIdx.z % nct;
  int nimg = blockIdx.z / nct;
  int co_base = ct*COB + ch*32;

  // bias init: D rows = co = co_base + cs*16 + quad*4 + r
  float bv[2][4];
  #pragma unroll
  for (int cs = 0; cs < 2; cs++)
    #pragma unroll
    for (int r = 0; r < 4; r++)
      bv[cs][r] = bias[co_base + cs*16 + quad*4 + r];
  f32x4 acc[2][2][4];   // [cs][ss][parity]
  #pragma unroll
  for (int cs = 0; cs < 2; cs++)
    #pragma unroll
    for (int ss = 0; ss < 2; ss++)
      #pragma unroll
      for (int p = 0; p < 4; p++)
        acc[cs][ss][p] = f32x4{bv[cs][0], bv[cs][1], bv[cs][2], bv[cs][3]};

  const short* xn = x + (size_t)nimg*Cin*Hin*Win;
  int nchunks = Cin >> 5;
  for (int ck = 0; ck < nchunks; ck++){
    int ci0 = ck << 5;
    __syncthreads();
    // stage x[ci0..ci0+32) rows i0-1..i0+1, cols j0-1..j0+TS, zero-padded OOB
    for (int idx = tid; idx < 3*COLS*32; idx += 256){
      int r   = idx / (COLS*32);
      int rem = idx - r*(COLS*32);
      int ci  = rem / COLS;
      int c   = rem - ci*COLS;
      int gi = i0 - 1 + r, gj = j0 - 1 + c;
      short v = 0;
      if ((unsigned)gi < (unsigned)Hin && (unsigned)gj < (unsigned)Win)
        v = xn[((size_t)(ci0+ci)*Hin + gi)*Win + gj];
      lds[(r*COLS + c)*CIP + ci] = v;
    }
    __syncthreads();
    // preload B-frags (x) for the 9 shifts x 2 spatial subtiles
    short8 bf[9][2];
    #pragma unroll
    for (int dr = 0; dr < 3; dr++)
      #pragma unroll
      for (int dc = 0; dc < 3; dc++)
        #pragma unroll
        for (int ss = 0; ss < 2; ss++){
          int col = sh*32 + ss*16 + n15 + dc;     // (1 + n + dc-1) folded
          bf[dr*3+dc][ss] = *(const short8*)&lds[(dr*COLS + col)*CIP + quad*8];
        }
    const short* wbase = wb + ci0 + quad*8;
    #pragma unroll
    for (int ph = 0; ph < 2; ph++)
      #pragma unroll
      for (int pw = 0; pw < 2; pw++){
        int p = ph*2 + pw;
        #pragma unroll
        for (int u = 0; u < 2; u++)
          #pragma unroll
          for (int v = 0; v < 2; v++){
            int tap  = (ph + 2*u)*4 + (pw + 2*v);
            int sidx = (u + ph)*3 + (v + pw);
            #pragma unroll
            for (int cs = 0; cs < 2; cs++){
              short8 af = *(const short8*)(wbase +
                  (size_t)(tap*Cout + co_base + cs*16 + n15)*Cin);
              #pragma unroll
              for (int ss = 0; ss < 2; ss++)
                acc[cs][ss][p] = __builtin_amdgcn_mfma_f32_16x16x32_bf16(
                    af, bf[sidx][ss], acc[cs][ss][p], 0, 0, 0);
            }
          }
      }
  }
  // epilogue: D rows = co, cols = spatial; pack pw pair -> bf16x2 dword
  int Hout = Hin*2, Wout = Win*2;
  #pragma unroll
  for (int cs = 0; cs < 2; cs++)
    #pragma unroll
    for (int ss = 0; ss < 2; ss++){
      int j_in = j0 + sh*32 + ss*16 + n15;
      #pragma unroll
      for (int ph = 0; ph < 2; ph++)
        #pragma unroll
        for (int r = 0; r < 4; r++){
          int co_l = co_base + cs*16 + quad*4 + r;
          float v0 = acc[cs][ss][ph*2+0][r];
          float v1 = acc[cs][ss][ph*2+1][r];
          if (relu){ v0 = fmaxf(v0, 0.f); v1 = fmaxf(v1, 0.f); }
          unsigned pk = ((unsigned)bfbits(v1) << 16) | (unsigned)bfbits(v0);
          *(unsigned*)&y[((size_t)(nimg*Cout + co_l)*Hout + 2*i0 + ph)*Wout + 2*j_in] = pk;
        }
    }
}

// ---------------- out conv: 3x3 p=1 s=1, Cout=3, f32 out ----------------
__global__ void conv3x3_out(const bf16* __restrict__ x, const float* __restrict__ wp,
                            const float* __restrict__ bias, float* __restrict__ y,
                            int Cin, int H, int W)
{
  int sp = blockIdx.x*256 + threadIdx.x;
  if (sp >= H*W) return;
  int oh = sp / W, ow = sp - oh*W;
  int n = blockIdx.z;
  float a0 = bias[0], a1 = bias[1], a2 = bias[2];
  const bf16* xn = x + (size_t)n*Cin*H*W;
  size_t HW = (size_t)H*W;
  for (int kh=0; kh<3; kh++){
    int ih = oh - 1 + kh;
    bool vh = ((unsigned)ih < (unsigned)H);
    for (int kw=0; kw<3; kw++){
      int iw = ow - 1 + kw;
      bool v = vh && ((unsigned)iw < (unsigned)W);
      const float* wr = wp + (size_t)(kh*3+kw)*Cin*3;
      const bf16* xp = xn + (size_t)ih*W + iw;
      for (int ci=0; ci<Cin; ci++){
        float xv = v ? ldf(xp + (size_t)ci*HW) : 0.f;
        a0 = fmaf(xv, wr[ci*3+0], a0);
        a1 = fmaf(xv, wr[ci*3+1], a1);
        a2 = fmaf(xv, wr[ci*3+2], a2);
      }
    }
  }
  float* yp = y + (size_t)n*3*HW + sp;
  yp[0]    = a0;
  yp[HW]   = a1;
  yp[2*HW] = a2;
}

// ---------------- workspace layout (bytes) ----------------
static const size_t W_WENC0 = 0;           //  24,576 f32
static const size_t W_WENC1 = 24576;       //  2,097,152
static const size_t W_WENC2 = 2121728;     //  8,388,608
static const size_t W_WPROJ = 10510336;    //  131,072
static const size_t W_WOUT  = 10641408;    //  13,824
static const size_t W_D0B   = 10655232;    //  1,048,576 bf16 [tap][co][ci]
static const size_t W_D1B   = 11703808;    //  4,194,304
static const size_t W_D2B   = 15898112;    //  1,048,576
static const size_t W_BYTES = 16946688;
// per-image activations:
//   A (16 MiB): h0 f32 (8 MiB) then d2 bf16 (16 MiB)
//   Bg (8 MiB): h1 f32 (4 MiB) then d1 bf16 (8 MiB)
//   C  (4 MiB): h2 f32 (2 MiB) then d0 bf16 (4 MiB)
//   zqs bf16 (128 KiB)
static const size_t PER_IMG = 29491200;

extern "C" void kernel_launch(void* const* d_in, const int* in_sizes, int n_in,
                              void* d_out, int out_size, void* d_ws, size_t ws_size,
                              hipStream_t stream)
{
  const float* x      = (const float*)d_in[0];
  const float* enc_w0 = (const float*)d_in[1];
  const float* enc_b0 = (const float*)d_in[2];
  const float* enc_w1 = (const float*)d_in[3];
  const float* enc_b1 = (const float*)d_in[4];
  const float* enc_w2 = (const float*)d_in[5];
  const float* enc_b2 = (const float*)d_in[6];
  const float* proj_w = (const float*)d_in[7];
  const float* proj_b = (const float*)d_in[8];
  const float* dec_w0 = (const float*)d_in[9];
  const float* dec_b0 = (const float*)d_in[10];
  const float* dec_w1 = (const float*)d_in[11];
  const float* dec_b1 = (const float*)d_in[12];
  const float* dec_w2 = (const float*)d_in[13];
  const float* dec_b2 = (const float*)d_in[14];
  const float* out_w  = (const float*)d_in[15];
  const float* out_b  = (const float*)d_in[16];
  const float* cb     = (const float*)d_in[17];

  float* out    = (float*)d_out;
  float* recon  = out;             // 16*3*256*256 = 3,145,728 f32
  float* z_out  = out + 3145728;   // 16*64*32*32  = 1,048,576 f32
  float* zq_out = out + 4194304;   // 16*64*32*32  = 1,048,576 f32

  char* ws = (char*)d_ws;
  float* wenc0 = (float*)(ws + W_WENC0);
  float* wenc1 = (float*)(ws + W_WENC1);
  float* wenc2 = (float*)(ws + W_WENC2);
  float* wproj = (float*)(ws + W_WPROJ);
  float* wout  = (float*)(ws + W_WOUT);
  short* wd0b  = (short*)(ws + W_D0B);
  short* wd1b  = (short*)(ws + W_D1B);
  short* wd2b  = (short*)(ws + W_D2B);

  // pick the largest chunk size that fits ws_size
  int B = 16;
  while (B > 1 && W_BYTES + (size_t)B*PER_IMG > ws_size) B >>= 1;

  char* act = ws + W_BYTES;
  size_t szA  = (size_t)B*16777216;
  size_t szBg = (size_t)B*8388608;
  size_t szC  = (size_t)B*4194304;
  float* h0  = (float*)(act);
  bf16*  d2  = (bf16*) (act);
  float* h1  = (float*)(act + szA);
  bf16*  d1  = (bf16*) (act + szA);
  float* h2  = (float*)(act + szA + szBg);
  bf16*  d0  = (bf16*) (act + szA + szBg);
  bf16*  zqs = (bf16*) (act + szA + szBg + szC);

  auto nb = [](int total){ return dim3((unsigned)((total + 255) / 256)); };

  // repack weights (once per call)
  repack_tco<<<nb(128*3*16),  256, 0, stream>>>(enc_w0, wenc0, 128, 3, 16);
  repack_tco<<<nb(256*128*16),256, 0, stream>>>(enc_w1, wenc1, 256, 128, 16);
  repack_tco<<<nb(512*256*16),256, 0, stream>>>(enc_w2, wenc2, 512, 256, 16);
  repack_tco<<<nb(64*512*1),  256, 0, stream>>>(proj_w, wproj, 64, 512, 1);
  repack_tco<<<nb(3*128*9),   256, 0, stream>>>(out_w, wout, 3, 128, 9);
  repack_tcc_bf16<<<nb(512*64*16), 256, 0, stream>>>(dec_w0, wd0b, 512, 64);
  repack_tcc_bf16<<<nb(256*512*16),256, 0, stream>>>(dec_w1, wd1b, 256, 512);
  repack_tcc_bf16<<<nb(128*256*16),256, 0, stream>>>(dec_w2, wd2b, 128, 256);

  for (int n0 = 0; n0 < 16; n0 += B){
    const float* xc  = x      + (size_t)n0*3*65536;
    float* reconc    = recon  + (size_t)n0*3*65536;
    float* z_outc    = z_out  + (size_t)n0*65536;
    float* zq_outc   = zq_out + (size_t)n0*65536;

    conv4x4s2<8><<<dim3(64,16,B), 256, 0, stream>>>(xc, wenc0, enc_b0, h0, 3,   256,256, 128, 128,128, 1);
    conv4x4s2<8><<<dim3(16,32,B), 256, 0, stream>>>(h0, wenc1, enc_b1, h1, 128, 128,128, 256, 64,64,   1);
    conv4x4s2<8><<<dim3(4, 64,B), 256, 0, stream>>>(h1, wenc2, enc_b2, h2, 256, 64,64,   512, 32,32,   1);
    conv1x1<8><<<dim3(4, 8, B), 256, 0, stream>>>(h2, wproj, proj_b, z_outc, 512, 1024, 64);

    vq_argmin<<<dim3(256*B), 256, 0, stream>>>(z_outc, cb, zq_outc, zqs);

    // decoder: MFMA implicit-GEMM transposed convs
    convT_mfma<32><<<dim3(1, 32, B*4), 256, 0, stream>>>(
        (const short*)zqs, wd0b, dec_b0, (short*)d0, 64, 32, 32, 512, 1);
    convT_mfma<64><<<dim3(1, 64, B*4), 256, 0, stream>>>(
        (const short*)d0, wd1b, dec_b1, (short*)d1, 512, 64, 64, 256, 1);
    convT_mfma<64><<<dim3(2, 128, B*2), 256, 0, stream>>>(
        (const short*)d1, wd2b, dec_b2, (short*)d2, 256, 128, 128, 128, 1);

    conv3x3_out<<<dim3(256,1,B), 256, 0, stream>>>(d2, wout, out_b, reconc, 128, 256, 256);
  }
}

// Round 6
// 6627.301 us; speedup vs baseline: 4.1964x; 1.5681x over previous
//
#include <hip/hip_runtime.h>
#include <hip/hip_bf16.h>

typedef __hip_bfloat16 bf16;
typedef __attribute__((ext_vector_type(8))) short short8;
typedef __attribute__((ext_vector_type(4))) float f32x4;

__device__ __forceinline__ float b2f(bf16 v){ return __bfloat162float(v); }
__device__ __forceinline__ bf16 f2b(float v){ return __float2bfloat16(v); }
__device__ __forceinline__ float ldf(const bf16* p){ return __bfloat162float(*p); }
__device__ __forceinline__ float ldf(const float* p){ return *p; }

__device__ __forceinline__ unsigned short bfbits(float v){
  union{ bf16 h; unsigned short u; } t; t.h = f2b(v); return t.u;
}

// ---------------- weight repacks ----------------
// w[Cout][Cin][KK] f32 -> o[KK][Cin][Cout] f32  (enc0 / proj / out conv)
__global__ void repack_tco(const float* __restrict__ w, float* __restrict__ o,
                           int Cout, int Cin, int KK){
  int i = blockIdx.x*256 + threadIdx.x;
  int total = Cout*Cin*KK;
  if (i >= total) return;
  int co = i / (Cin*KK);
  int r  = i - co*(Cin*KK);
  int ci = r / KK;
  int t  = r - ci*KK;
  o[((size_t)t*Cin + ci)*Cout + co] = w[i];
}

// w[Cout][Cin][16] f32 -> o[tap][Cout][Cin] bf16  (MFMA A-operand, enc+dec)
__global__ void repack_tcc_bf16(const float* __restrict__ w, short* __restrict__ o,
                                int Cout, int Cin){
  int i = blockIdx.x*256 + threadIdx.x;
  int total = Cout*Cin*16;
  if (i >= total) return;
  int co = i / (Cin*16);
  int r  = i - co*(Cin*16);
  int ci = r >> 4;
  int t  = r & 15;
  o[((size_t)t*Cout + co)*Cin + ci] = (short)bfbits(w[i]);
}

// ---------------- enc0: conv k=4 s=2 p=1, f32 accumulate, bf16 out ----------------
template<int CO_BLK>
__global__ void conv4x4s2(const float* __restrict__ x, const float* __restrict__ wp,
                          const float* __restrict__ bias, bf16* __restrict__ y,
                          int Cin, int Hin, int Win, int Cout, int Hout, int Wout,
                          int relu)
{
  int sp = blockIdx.x*256 + threadIdx.x;
  if (sp >= Hout*Wout) return;
  int oh = sp / Wout, ow = sp - oh*Wout;
  int n = blockIdx.z, co0 = blockIdx.y*CO_BLK;
  float acc[CO_BLK];
  #pragma unroll
  for (int j=0;j<CO_BLK;j++) acc[j] = bias[co0+j];
  const float* xn = x + (size_t)n*Cin*Hin*Win;
  size_t HWi = (size_t)Hin*Win;
  for (int kh=0; kh<4; kh++){
    int ih = 2*oh - 1 + kh;
    bool vh = ((unsigned)ih < (unsigned)Hin);
    for (int kw=0; kw<4; kw++){
      int iw = 2*ow - 1 + kw;
      bool v = vh && ((unsigned)iw < (unsigned)Win);
      const float* wr = wp + ((size_t)(kh*4+kw)*Cin)*Cout + co0;
      const float* xp = xn + (size_t)ih*Win + iw;
      for (int ci=0; ci<Cin; ci++){
        float xv = v ? xp[(size_t)ci*HWi] : 0.f;
        #pragma unroll
        for (int j=0;j<CO_BLK;j++)
          acc[j] = fmaf(xv, wr[(size_t)ci*Cout + j], acc[j]);
      }
    }
  }
  size_t HWo = (size_t)Hout*Wout;
  bf16* yp = y + ((size_t)n*Cout + co0)*HWo + sp;
  #pragma unroll
  for (int j=0;j<CO_BLK;j++){
    float r = acc[j];
    if (relu) r = fmaxf(r, 0.f);
    yp[(size_t)j*HWo] = f2b(r);
  }
}

// ---------------- enc1/enc2: conv k=4 s=2 p=1 via MFMA 16x16x32 bf16 ----------------
// out[oh][jj] needs input rows 2oh-1..2oh+2, col for (jj,kw) = 2*jj-1+kw.
// A = weights [tap][co][ci] (m=co, k=ci); B = x staged in LDS (k=ci, n=jj).
// TS=64: 4 waves = 2 spatial-halves x 2 co-halves (block 64sp x 64co).
// TS=32: 4 waves = 4 co-quarters (block 32sp x 128co).
template<int TS>
__global__ __launch_bounds__(256) void conv_enc_mfma(
    const short* __restrict__ x, const short* __restrict__ wb,
    const float* __restrict__ bias, short* __restrict__ y,
    int Cin, int Hin, int Win, int Cout, int relu)
{
  constexpr int SHW   = TS/32;
  constexpr int COB   = (4/SHW)*32;
  constexpr int ICOLS = 2*TS + 2;
  constexpr int CIP   = 40;
  __shared__ __align__(16) short lds[4*ICOLS*CIP];

  int tid  = threadIdx.x;
  int w    = tid >> 6, lane = tid & 63;
  int sh   = w % SHW, ch = w / SHW;
  int n15  = lane & 15, quad = lane >> 4;
  int oh   = blockIdx.y;
  int j0   = blockIdx.x * TS;
  int nct  = Cout / COB;
  int ct   = blockIdx.z % nct;
  int nimg = blockIdx.z / nct;
  int co_base = ct*COB + ch*32;
  int Hout = Hin >> 1, Wout = Win >> 1;

  float bv[2][4];
  #pragma unroll
  for (int cs = 0; cs < 2; cs++)
    #pragma unroll
    for (int r = 0; r < 4; r++)
      bv[cs][r] = bias[co_base + cs*16 + quad*4 + r];
  f32x4 acc[2][2];   // [cs][ss]
  #pragma unroll
  for (int cs = 0; cs < 2; cs++)
    #pragma unroll
    for (int ss = 0; ss < 2; ss++)
      acc[cs][ss] = f32x4{bv[cs][0], bv[cs][1], bv[cs][2], bv[cs][3]};

  const short* xn = x + (size_t)nimg*Cin*Hin*Win;
  size_t HWin = (size_t)Hin*Win;
  int nchunks = Cin >> 5;
  for (int ck = 0; ck < nchunks; ck++){
    int ci0 = ck << 5;
    __syncthreads();
    // stage rows 2oh-1..2oh+2, cols 2j0-1..2j0+2TS, 32 ci, zero-padded OOB
    for (int idx = tid; idx < 4*ICOLS*32; idx += 256){
      int r   = idx / (ICOLS*32);
      int rem = idx - r*(ICOLS*32);
      int ci  = rem / ICOLS;
      int c   = rem - ci*ICOLS;
      int gi = 2*oh - 1 + r, gj = 2*j0 - 1 + c;
      short v = 0;
      if ((unsigned)gi < (unsigned)Hin && (unsigned)gj < (unsigned)Win)
        v = xn[(size_t)(ci0+ci)*HWin + (size_t)gi*Win + gj];
      lds[(r*ICOLS + c)*CIP + ci] = v;
    }
    __syncthreads();
    #pragma unroll
    for (int kh = 0; kh < 4; kh++){
      short8 bfr[4][2];
      #pragma unroll
      for (int kw = 0; kw < 4; kw++)
        #pragma unroll
        for (int ss = 0; ss < 2; ss++){
          int col = 2*(sh*32 + ss*16 + n15) + kw;
          bfr[kw][ss] = *(const short8*)&lds[(kh*ICOLS + col)*CIP + quad*8];
        }
      #pragma unroll
      for (int kw = 0; kw < 4; kw++){
        int tap = kh*4 + kw;
        #pragma unroll
        for (int cs = 0; cs < 2; cs++){
          short8 af = *(const short8*)(wb +
              (size_t)(tap*Cout + co_base + cs*16 + n15)*Cin + ci0 + quad*8);
          #pragma unroll
          for (int ss = 0; ss < 2; ss++)
            acc[cs][ss] = __builtin_amdgcn_mfma_f32_16x16x32_bf16(
                af, bfr[kw][ss], acc[cs][ss], 0, 0, 0);
        }
      }
    }
  }
  // epilogue: D rows = co, cols = output col jj
  #pragma unroll
  for (int cs = 0; cs < 2; cs++)
    #pragma unroll
    for (int ss = 0; ss < 2; ss++){
      int jj = j0 + sh*32 + ss*16 + n15;
      #pragma unroll
      for (int r = 0; r < 4; r++){
        int co_l = co_base + cs*16 + quad*4 + r;
        float v = acc[cs][ss][r];
        if (relu) v = fmaxf(v, 0.f);
        y[((size_t)(nimg*Cout + co_l)*Hout + oh)*Wout + jj] = (short)bfbits(v);
      }
    }
}

// ---------------- proj: 1x1 conv (bf16 in); writes z (f32) straight to d_out ----------------
template<int CO_BLK>
__global__ void conv1x1(const bf16* __restrict__ x, const float* __restrict__ wp,
                        const float* __restrict__ bias, float* __restrict__ z,
                        int Cin, int HW, int Cout)
{
  int sp = blockIdx.x*256 + threadIdx.x;
  if (sp >= HW) return;
  int n = blockIdx.z, co0 = blockIdx.y*CO_BLK;
  float acc[CO_BLK];
  #pragma unroll
  for (int j=0;j<CO_BLK;j++) acc[j] = bias[co0+j];
  const bf16* xp = x + (size_t)n*Cin*HW + sp;
  for (int ci=0; ci<Cin; ci++){
    float xv = ldf(xp + (size_t)ci*HW);
    #pragma unroll
    for (int j=0;j<CO_BLK;j++)
      acc[j] = fmaf(xv, wp[(size_t)ci*Cout + co0 + j], acc[j]);
  }
  size_t base = ((size_t)n*Cout + co0)*HW + sp;
  #pragma unroll
  for (int j=0;j<CO_BLK;j++)
    z[base + (size_t)j*HW] = acc[j];
}

// ---------------- VQ: per-wave argmin over 1024 codes ----------------
__global__ void vq_argmin(const float* __restrict__ z, const float* __restrict__ cbf,
                          float* __restrict__ zq, bf16* __restrict__ zqst)
{
  __shared__ float lz[4][64];
  int t = threadIdx.x;
  int q = t >> 6, l = t & 63;
  int p = blockIdx.x*4 + q;
  int n = p >> 10, hw = p & 1023;
  size_t zbase = ((size_t)n*64)*1024 + hw;
  float zl = z[zbase + (size_t)l*1024];
  lz[q][l] = zl;
  __syncthreads();
  float best = 3.0e38f; int bi = 0;
  const float* zv = &lz[q][0];
  for (int c = l; c < 1024; c += 64){
    const float4* row = reinterpret_cast<const float4*>(cbf + (size_t)c*64);
    float d = 0.f;
    #pragma unroll
    for (int v4 = 0; v4 < 16; v4++){
      float4 cv = row[v4];
      int j0 = v4*4;
      float d0 = zv[j0+0]-cv.x; d = fmaf(d0,d0,d);
      float d1 = zv[j0+1]-cv.y; d = fmaf(d1,d1,d);
      float d2 = zv[j0+2]-cv.z; d = fmaf(d2,d2,d);
      float d3 = zv[j0+3]-cv.w; d = fmaf(d3,d3,d);
    }
    if (d < best){ best = d; bi = c; }
  }
  #pragma unroll
  for (int off = 32; off > 0; off >>= 1){
    float od = __shfl_down(best, off, 64);
    int   oi = __shfl_down(bi,  off, 64);
    if (od < best || (od == best && oi < bi)){ best = od; bi = oi; }
  }
  bi = __shfl(bi, 0, 64);
  float qv = cbf[(size_t)bi*64 + l];
  size_t oidx = zbase + (size_t)l*1024;
  zq[oidx]   = qv;
  zqst[oidx] = f2b(zl + (qv - zl));
}

// ---------------- decoder: convT k=4 s=2 via MFMA 16x16x32 bf16 ----------------
template<int TS>
__global__ __launch_bounds__(256) void convT_mfma(
    const short* __restrict__ x, const short* __restrict__ wb,
    const float* __restrict__ bias, short* __restrict__ y,
    int Cin, int Hin, int Win, int Cout, int relu)
{
  constexpr int SHW  = TS/32;
  constexpr int COB  = (4/SHW)*32;
  constexpr int COLS = TS + 2;
  constexpr int CIP  = 40;
  __shared__ __align__(16) short lds[3*COLS*CIP];

  int tid  = threadIdx.x;
  int w    = tid >> 6, lane = tid & 63;
  int sh   = w % SHW, ch = w / SHW;
  int n15  = lane & 15, quad = lane >> 4;
  int i0   = blockIdx.y;
  int j0   = blockIdx.x * TS;
  int nct  = Cout / COB;
  int ct   = blockIdx.z % nct;
  int nimg = blockIdx.z / nct;
  int co_base = ct*COB + ch*32;

  float bv[2][4];
  #pragma unroll
  for (int cs = 0; cs < 2; cs++)
    #pragma unroll
    for (int r = 0; r < 4; r++)
      bv[cs][r] = bias[co_base + cs*16 + quad*4 + r];
  f32x4 acc[2][2][4];   // [cs][ss][parity]
  #pragma unroll
  for (int cs = 0; cs < 2; cs++)
    #pragma unroll
    for (int ss = 0; ss < 2; ss++)
      #pragma unroll
      for (int p = 0; p < 4; p++)
        acc[cs][ss][p] = f32x4{bv[cs][0], bv[cs][1], bv[cs][2], bv[cs][3]};

  const short* xn = x + (size_t)nimg*Cin*Hin*Win;
  int nchunks = Cin >> 5;
  for (int ck = 0; ck < nchunks; ck++){
    int ci0 = ck << 5;
    __syncthreads();
    for (int idx = tid; idx < 3*COLS*32; idx += 256){
      int r   = idx / (COLS*32);
      int rem = idx - r*(COLS*32);
      int ci  = rem / COLS;
      int c   = rem - ci*COLS;
      int gi = i0 - 1 + r, gj = j0 - 1 + c;
      short v = 0;
      if ((unsigned)gi < (unsigned)Hin && (unsigned)gj < (unsigned)Win)
        v = xn[((size_t)(ci0+ci)*Hin + gi)*Win + gj];
      lds[(r*COLS + c)*CIP + ci] = v;
    }
    __syncthreads();
    short8 bf[9][2];
    #pragma unroll
    for (int dr = 0; dr < 3; dr++)
      #pragma unroll
      for (int dc = 0; dc < 3; dc++)
        #pragma unroll
        for (int ss = 0; ss < 2; ss++){
          int col = sh*32 + ss*16 + n15 + dc;
          bf[dr*3+dc][ss] = *(const short8*)&lds[(dr*COLS + col)*CIP + quad*8];
        }
    const short* wbase = wb + ci0 + quad*8;
    #pragma unroll
    for (int ph = 0; ph < 2; ph++)
      #pragma unroll
      for (int pw = 0; pw < 2; pw++){
        int p = ph*2 + pw;
        #pragma unroll
        for (int u = 0; u < 2; u++)
          #pragma unroll
          for (int v = 0; v < 2; v++){
            int tap  = (ph + 2*u)*4 + (pw + 2*v);
            int sidx = (u + ph)*3 + (v + pw);
            #pragma unroll
            for (int cs = 0; cs < 2; cs++){
              short8 af = *(const short8*)(wbase +
                  (size_t)(tap*Cout + co_base + cs*16 + n15)*Cin);
              #pragma unroll
              for (int ss = 0; ss < 2; ss++)
                acc[cs][ss][p] = __builtin_amdgcn_mfma_f32_16x16x32_bf16(
                    af, bf[sidx][ss], acc[cs][ss][p], 0, 0, 0);
            }
          }
      }
  }
  int Hout = Hin*2, Wout = Win*2;
  #pragma unroll
  for (int cs = 0; cs < 2; cs++)
    #pragma unroll
    for (int ss = 0; ss < 2; ss++){
      int j_in = j0 + sh*32 + ss*16 + n15;
      #pragma unroll
      for (int ph = 0; ph < 2; ph++)
        #pragma unroll
        for (int r = 0; r < 4; r++){
          int co_l = co_base + cs*16 + quad*4 + r;
          float v0 = acc[cs][ss][ph*2+0][r];
          float v1 = acc[cs][ss][ph*2+1][r];
          if (relu){ v0 = fmaxf(v0, 0.f); v1 = fmaxf(v1, 0.f); }
          unsigned pk = ((unsigned)bfbits(v1) << 16) | (unsigned)bfbits(v0);
          *(unsigned*)&y[((size_t)(nimg*Cout + co_l)*Hout + 2*i0 + ph)*Wout + 2*j_in] = pk;
        }
    }
}

// ---------------- out conv: 3x3 p=1 s=1, Cout=3, f32 out ----------------
__global__ void conv3x3_out(const bf16* __restrict__ x, const float* __restrict__ wp,
                            const float* __restrict__ bias, float* __restrict__ y,
                            int Cin, int H, int W)
{
  int sp = blockIdx.x*256 + threadIdx.x;
  if (sp >= H*W) return;
  int oh = sp / W, ow = sp - oh*W;
  int n = blockIdx.z;
  float a0 = bias[0], a1 = bias[1], a2 = bias[2];
  const bf16* xn = x + (size_t)n*Cin*H*W;
  size_t HW = (size_t)H*W;
  for (int kh=0; kh<3; kh++){
    int ih = oh - 1 + kh;
    bool vh = ((unsigned)ih < (unsigned)H);
    for (int kw=0; kw<3; kw++){
      int iw = ow - 1 + kw;
      bool v = vh && ((unsigned)iw < (unsigned)W);
      const float* wr = wp + (size_t)(kh*3+kw)*Cin*3;
      const bf16* xp = xn + (size_t)ih*W + iw;
      for (int ci=0; ci<Cin; ci++){
        float xv = v ? ldf(xp + (size_t)ci*HW) : 0.f;
        a0 = fmaf(xv, wr[ci*3+0], a0);
        a1 = fmaf(xv, wr[ci*3+1], a1);
        a2 = fmaf(xv, wr[ci*3+2], a2);
      }
    }
  }
  float* yp = y + (size_t)n*3*HW + sp;
  yp[0]    = a0;
  yp[HW]   = a1;
  yp[2*HW] = a2;
}

// ---------------- workspace layout (bytes) ----------------
static const size_t W_WENC0 = 0;           //  24,576 f32 [tap][ci][co]
static const size_t W_WPROJ = 24576;       //  131,072 f32
static const size_t W_WOUT  = 155648;      //  13,824 f32
static const size_t W_E1B   = 169472;      //  1,048,576 bf16 [tap][co][ci]
static const size_t W_E2B   = 1218048;     //  4,194,304
static const size_t W_D0B   = 5412352;     //  1,048,576
static const size_t W_D1B   = 6460928;     //  4,194,304
static const size_t W_D2B   = 10655232;    //  1,048,576
static const size_t W_BYTES = 11703808;
// per-image activations (lifetime-aliased):
//   A (16 MiB): h0 bf16 (4 MiB) then d2 bf16 (16 MiB)
//   Bg (8 MiB): h1 bf16 (2 MiB) then d1 bf16 (8 MiB)
//   C  (4 MiB): h2 bf16 (1 MiB) then d0 bf16 (4 MiB)
//   zqs bf16 (128 KiB)
static const size_t PER_IMG = 29491200;

extern "C" void kernel_launch(void* const* d_in, const int* in_sizes, int n_in,
                              void* d_out, int out_size, void* d_ws, size_t ws_size,
                              hipStream_t stream)
{
  const float* x      = (const float*)d_in[0];
  const float* enc_w0 = (const float*)d_in[1];
  const float* enc_b0 = (const float*)d_in[2];
  const float* enc_w1 = (const float*)d_in[3];
  const float* enc_b1 = (const float*)d_in[4];
  const float* enc_w2 = (const float*)d_in[5];
  const float* enc_b2 = (const float*)d_in[6];
  const float* proj_w = (const float*)d_in[7];
  const float* proj_b = (const float*)d_in[8];
  const float* dec_w0 = (const float*)d_in[9];
  const float* dec_b0 = (const float*)d_in[10];
  const float* dec_w1 = (const float*)d_in[11];
  const float* dec_b1 = (const float*)d_in[12];
  const float* dec_w2 = (const float*)d_in[13];
  const float* dec_b2 = (const float*)d_in[14];
  const float* out_w  = (const float*)d_in[15];
  const float* out_b  = (const float*)d_in[16];
  const float* cb     = (const float*)d_in[17];

  float* out    = (float*)d_out;
  float* recon  = out;             // 16*3*256*256 = 3,145,728 f32
  float* z_out  = out + 3145728;   // 16*64*32*32  = 1,048,576 f32
  float* zq_out = out + 4194304;   // 16*64*32*32  = 1,048,576 f32

  char* ws = (char*)d_ws;
  float* wenc0 = (float*)(ws + W_WENC0);
  float* wproj = (float*)(ws + W_WPROJ);
  float* wout  = (float*)(ws + W_WOUT);
  short* we1b  = (short*)(ws + W_E1B);
  short* we2b  = (short*)(ws + W_E2B);
  short* wd0b  = (short*)(ws + W_D0B);
  short* wd1b  = (short*)(ws + W_D1B);
  short* wd2b  = (short*)(ws + W_D2B);

  int B = 16;
  while (B > 1 && W_BYTES + (size_t)B*PER_IMG > ws_size) B >>= 1;

  char* act = ws + W_BYTES;
  size_t szA  = (size_t)B*16777216;
  size_t szBg = (size_t)B*8388608;
  size_t szC  = (size_t)B*4194304;
  bf16*  h0  = (bf16*) (act);
  bf16*  d2  = (bf16*) (act);
  bf16*  h1  = (bf16*) (act + szA);
  bf16*  d1  = (bf16*) (act + szA);
  bf16*  h2  = (bf16*) (act + szA + szBg);
  bf16*  d0  = (bf16*) (act + szA + szBg);
  bf16*  zqs = (bf16*) (act + szA + szBg + szC);

  auto nb = [](int total){ return dim3((unsigned)((total + 255) / 256)); };

  // repack weights (once per call)
  repack_tco<<<nb(128*3*16),  256, 0, stream>>>(enc_w0, wenc0, 128, 3, 16);
  repack_tco<<<nb(64*512*1),  256, 0, stream>>>(proj_w, wproj, 64, 512, 1);
  repack_tco<<<nb(3*128*9),   256, 0, stream>>>(out_w, wout, 3, 128, 9);
  repack_tcc_bf16<<<nb(256*128*16),256, 0, stream>>>(enc_w1, we1b, 256, 128);
  repack_tcc_bf16<<<nb(512*256*16),256, 0, stream>>>(enc_w2, we2b, 512, 256);
  repack_tcc_bf16<<<nb(512*64*16), 256, 0, stream>>>(dec_w0, wd0b, 512, 64);
  repack_tcc_bf16<<<nb(256*512*16),256, 0, stream>>>(dec_w1, wd1b, 256, 512);
  repack_tcc_bf16<<<nb(128*256*16),256, 0, stream>>>(dec_w2, wd2b, 128, 256);

  for (int n0 = 0; n0 < 16; n0 += B){
    const float* xc  = x      + (size_t)n0*3*65536;
    float* reconc    = recon  + (size_t)n0*3*65536;
    float* z_outc    = z_out  + (size_t)n0*65536;
    float* zq_outc   = zq_out + (size_t)n0*65536;

    // encoder
    conv4x4s2<8><<<dim3(64,16,B), 256, 0, stream>>>(xc, wenc0, enc_b0, h0, 3, 256,256, 128, 128,128, 1);
    conv_enc_mfma<64><<<dim3(1, 64, B*4), 256, 0, stream>>>(
        (const short*)h0, we1b, enc_b1, (short*)h1, 128, 128, 128, 256, 1);
    conv_enc_mfma<32><<<dim3(1, 32, B*4), 256, 0, stream>>>(
        (const short*)h1, we2b, enc_b2, (short*)h2, 256, 64, 64, 512, 1);
    conv1x1<8><<<dim3(4, 8, B), 256, 0, stream>>>(h2, wproj, proj_b, z_outc, 512, 1024, 64);

    vq_argmin<<<dim3(256*B), 256, 0, stream>>>(z_outc, cb, zq_outc, zqs);

    // decoder
    convT_mfma<32><<<dim3(1, 32, B*4), 256, 0, stream>>>(
        (const short*)zqs, wd0b, dec_b0, (short*)d0, 64, 32, 32, 512, 1);
    convT_mfma<64><<<dim3(1, 64, B*4), 256, 0, stream>>>(
        (const short*)d0, wd1b, dec_b1, (short*)d1, 512, 64, 64, 256, 1);
    convT_mfma<64><<<dim3(2, 128, B*2), 256, 0, stream>>>(
        (const short*)d1, wd2b, dec_b2, (short*)d2, 256, 128, 128, 128, 1);

    conv3x3_out<<<dim3(256,1,B), 256, 0, stream>>>(d2, wout, out_b, reconc, 128, 256, 256);
  }
}